// Round 4
// baseline (424.461 us; speedup 1.0000x reference)
//
#include <hip/hip_runtime.h>
#include <hip/hip_bf16.h>
#include <math.h>

#define NB 2
#define LL 64
#define NMESH 100000
#define HEADS_O 8
#define DHC 64
#define DMODEL 512
#define DINNER 1024
#define DSTATE 64
#define NH 16
#define CONVDIM 1152
#define DINPROJ 2208
#define DOUT 256

typedef __attribute__((ext_vector_type(8))) short short8v;   // 8 x bf16
typedef __attribute__((ext_vector_type(4))) float f32x4;

__device__ __forceinline__ unsigned short f2bf(float f) {
  union { float f; unsigned u; } v; v.f = f;
  unsigned u = v.u;
  u += 0x7FFFu + ((u >> 16) & 1u);
  return (unsigned short)(u >> 16);
}

__device__ __forceinline__ float dot4(float4 a, const float* b) {
  return a.x*b[0] + a.y*b[1] + a.z*b[2] + a.w*b[3];
}

__device__ __forceinline__ float silu(float s) { return s / (1.f + expf(-s)); }

// depthwise 3-tap conv + silu on the xBC slab of zx. c is CONVDIM index.
__device__ __forceinline__ float conv_silu(const float* __restrict__ zx,
                                           const float* __restrict__ cw,
                                           const float* __restrict__ cb,
                                           int b, int l, int c) {
  float s = cb[c];
  #pragma unroll
  for (int k = 0; k < 3; ++k) {
    int tt = l - 1 + k;
    if (tt >= 0 && tt < LL)
      s += cw[c*3 + k] * zx[(size_t)(b*LL + tt)*DINPROJ + DINNER + c];
  }
  return silu(s);
}

// ---------------------------------------------------------------- K1: in_proj (weight-streaming)
__global__ void k_inproj(const float* __restrict__ st, const float* __restrict__ w,
                         float* __restrict__ zx) {
  int oc = blockIdx.x;             // 0..8 : o = oc*256 + t
  int blc = blockIdx.y;            // 0..15: bl = blc*8 + r
  int t = threadIdx.x;
  __shared__ float u[8][DMODEL];   // 16 KB
  for (int idx = t; idx < 8*DMODEL; idx += 256) {
    int r = idx >> 9, m = idx & 511;
    int bl = blc*8 + r; int b = bl >> 6, l = bl & 63;
    u[r][m] = st[((size_t)(b*HEADS_O + (m >> 6))*LL + l)*DHC + (m & 63)];
  }
  __syncthreads();
  int o = oc*256 + t;
  if (o < DINPROJ) {
    const float4* wr = (const float4*)(w + (size_t)o*DMODEL);
    float acc[8] = {0,0,0,0,0,0,0,0};
    for (int m4 = 0; m4 < DMODEL/4; ++m4) {
      float4 wv = wr[m4];
      #pragma unroll
      for (int r = 0; r < 8; ++r) acc[r] += dot4(wv, &u[r][m4*4]);
    }
    #pragma unroll
    for (int r = 0; r < 8; ++r)
      zx[(size_t)(blc*8 + r)*DINPROJ + o] = acc[r];
  }
}

// ---------------------------------------------------------------- K2: fused conv+dt+SSD scan
__global__ void k_scanconv(const float* __restrict__ zx, const float* __restrict__ cw,
                           const float* __restrict__ cb, const float* __restrict__ dtb,
                           const float* __restrict__ A_log, float* __restrict__ ybuf) {
  int blk = blockIdx.x;
  int s = blk >> 4, hh = blk & 15;
  int b = s & 1;
  bool rev = (s >= 2);
  int t = threadIdx.x;
  int wv = t >> 6, lane = t & 63;
  __shared__ float Bs[64*68];
  __shared__ float Cs[64*68];
  __shared__ float Xs[64*64];
  __shared__ float dts[64];
  __shared__ float Dc[64];

  for (int id = t; id < 4096; id += 256) {
    int tt0 = id >> 6, n = id & 63;
    int tt = rev ? (63 - tt0) : tt0;
    Xs[tt0*64 + n] = conv_silu(zx, cw, cb, b, tt, hh*64 + n);
    Bs[tt0*68 + n] = conv_silu(zx, cw, cb, b, tt, DINNER + n);
    Cs[tt0*68 + n] = conv_silu(zx, cw, cb, b, tt, DINNER + DSTATE + n);
  }
  if (t < 64) {
    int tt = rev ? (63 - t) : t;
    int ch = rev ? (16 + hh) : hh;
    float v = zx[(size_t)(b*LL + tt)*DINPROJ + (DINNER + CONVDIM) + ch] + dtb[hh];
    dts[t] = (v > 20.f) ? v : log1pf(expf(v));
  }
  __syncthreads();
  if (t < 64) {
    float v = dts[t];
    #pragma unroll
    for (int m = 1; m < 64; m <<= 1) {
      float o = __shfl_up(v, m, 64);
      if (lane >= m) v += o;
    }
    Dc[t] = v;
  }
  __syncthreads();
  float A = -expf(A_log[hh]);
  float g[16];
  #pragma unroll
  for (int i = 0; i < 16; ++i) {
    int tt = wv + 4*i;
    int ta = lane;
    float gv = 0.f;
    if (ta <= tt) {
      const float* Br = &Bs[ta*68];
      const float* Cr = &Cs[tt*68];
      float dot = 0.f;
      #pragma unroll
      for (int n4 = 0; n4 < 16; ++n4) {
        float4 bv = *(const float4*)&Br[n4*4];
        float4 cv = *(const float4*)&Cr[n4*4];
        dot += bv.x*cv.x + bv.y*cv.y + bv.z*cv.z + bv.w*cv.w;
      }
      gv = dot * expf(A * (Dc[tt] - Dc[ta])) * dts[ta];
    }
    g[i] = gv;
  }
  __syncthreads();
  #pragma unroll
  for (int i = 0; i < 16; ++i) Bs[(wv + 4*i)*64 + lane] = g[i];
  __syncthreads();
  for (int id = t; id < 4096; id += 256) {
    int tt = id >> 6, p = id & 63;
    float y = 0.f;
    for (int ta = 0; ta <= tt; ++ta) y += Bs[tt*64 + ta] * Xs[ta*64 + p];
    ybuf[(size_t)(s*LL + tt)*DINNER + hh*64 + p] = y;
  }
}

// ---------------------------------------------------------------- K3: combine + gate + RMS + out_proj + mfrag (fused)
__global__ void k_combo(const float* __restrict__ zx, const float* __restrict__ yb,
                        const float* __restrict__ fcD, const float* __restrict__ Dd,
                        const float* __restrict__ nw, const float* __restrict__ opw,
                        const float* __restrict__ tow, const float* __restrict__ cw,
                        const float* __restrict__ cb, unsigned short* __restrict__ mfp) {
  int bl = blockIdx.x; int b = bl >> 6, l = bl & 63;
  int t = threadIdx.x;
  __shared__ float xog[DINNER];
  __shared__ float yrow[DINNER];
  __shared__ float ohs[DMODEL];
  __shared__ float diag[NH];
  __shared__ float wsum[4];
  // x_og via on-the-fly conv+silu
  #pragma unroll
  for (int i = 0; i < 4; ++i) {
    int c = t + 256*i;
    xog[c] = conv_silu(zx, cw, cb, b, l, c);
  }
  __syncthreads();
  {
    int hh = t >> 4, j = t & 15;
    const float* fr = fcD + (size_t)hh*DINNER;
    float acc = 0.f;
    for (int k = 0; k < 64; ++k) acc += xog[j + 16*k] * fr[j + 16*k];
    #pragma unroll
    for (int m = 8; m >= 1; m >>= 1) acc += __shfl_xor(acc, m, 64);
    if (j == 0) diag[hh] = acc + Dd[hh];
  }
  __syncthreads();
  float ss = 0.f;
  float y2v[4];
  #pragma unroll
  for (int i = 0; i < 4; ++i) {
    int c = t + 256*i;
    float yf = (l == 0)  ? 0.f : yb[(size_t)(b*LL + l - 1)*DINNER + c];
    float yw = (l == 63) ? 0.f : yb[(size_t)((2+b)*LL + 62 - l)*DINNER + c];
    float y1 = yf + yw + xog[c]*diag[c >> 6];
    float z = zx[(size_t)bl*DINPROJ + c];
    float y2 = y1 * silu(z);
    y2v[i] = y2;
    ss += y2*y2;
  }
  #pragma unroll
  for (int m = 32; m >= 1; m >>= 1) ss += __shfl_xor(ss, m, 64);
  if ((t & 63) == 0) wsum[t >> 6] = ss;
  __syncthreads();
  float tot = wsum[0] + wsum[1] + wsum[2] + wsum[3];
  float scale = rsqrtf(tot * (1.f/1024.f) + 1e-5f);
  #pragma unroll
  for (int i = 0; i < 4; ++i) {
    int c = t + 256*i;
    yrow[c] = y2v[i] * scale * nw[c];
  }
  __syncthreads();
  // out_proj: 512 outs, 2 per thread
  #pragma unroll
  for (int oi = 0; oi < 2; ++oi) {
    int o = t + 256*oi;
    const float4* wr = (const float4*)(opw + (size_t)o*DINNER);
    float acc = 0.f;
    #pragma unroll 4
    for (int k4 = 0; k4 < DINNER/4; ++k4) acc += dot4(wr[k4], &yrow[k4*4]);
    ohs[o] = acc;
  }
  __syncthreads();
  // mfrag: M[b,h,g,d] = sum_c ohs[h*64+c]*tow[d,h*64+c], this block owns g = l
  int g = l;
  int kkq = g >> 5;
  int lnhi = ((g & 31) >> 3) << 4;
  int j = g & 7;
  #pragma unroll
  for (int ii = 0; ii < 8; ++ii) {
    int idx = t + 256*ii;            // (h,d)
    int h = idx >> 8, d = idx & 255;
    const float4* wr = (const float4*)(tow + (size_t)d*DMODEL + h*64);
    const float* op = &ohs[h*64];
    float acc = 0.f;
    #pragma unroll
    for (int c4 = 0; c4 < 16; ++c4) acc += dot4(wr[c4], &op[c4*4]);
    int ln = (d & 15) | lnhi;
    mfp[((((size_t)(b*HEADS_O + h)*2 + kkq)*16 + (d >> 4))*64 + ln)*8 + j] = f2bf(acc);
  }
}

// ---------------------------------------------------------------- K4: big GEMM, burst-streaming
// out[b,n,d] = sum_{h,g} W[b,h,n,g]*M[b,h,g,d] + tob[d]
// Block: 64 rows x 128 cols (ch halves the 256 cols). B panel (full K=512 for
// this col-half) in LDS, staged in two 4-h halves of 32 KB via global_load_lds.
// Each lane bursts its WHOLE A K-row (32 dwordx4, 128 VGPR) so loads cannot be
// sunk; 3 barriers per block total; waves otherwise free-run -> BW-bound.
#define GLDS(g, l) __builtin_amdgcn_global_load_lds( \
    (const __attribute__((address_space(1))) void*)(g), \
    (__attribute__((address_space(3))) void*)(l), 16, 0, 0)

__global__ __launch_bounds__(256, 2) void k_out_gemm(const float* __restrict__ W,
                                                     const unsigned short* __restrict__ mf,
                                                     const float* __restrict__ tob,
                                                     float* __restrict__ out) {
  int bx = blockIdx.x;              // chunk*2 + ch  (ch fastest -> L3 pairing)
  int b  = blockIdx.y;
  int chunk = bx >> 1, ch = bx & 1;
  int n0 = chunk * 64;
  int tid = threadIdx.x;
  int wv = tid >> 6, lane = tid & 63;
  int r16 = lane & 15, kg = lane >> 4;

  // [hl 0..3][kk][ctl 0..7][512 shorts] = 64 KB
  __shared__ __align__(16) unsigned short lsB[4*2*8*512];

  int row = n0 + wv*16 + r16;
  if (row >= NMESH) row = NMESH - 1;
  const float* wb = W + (size_t)b*HEADS_O*NMESH*64 + (size_t)row*64 + kg*8;
  const unsigned short* mfb = mf + (size_t)b*(HEADS_O*2*16*512);

  // ---- stage B half 0 (h 0..3): 16 sweeps x 256 thr x 16B
  #pragma unroll
  for (int sw = 0; sw < 16; ++sw) {
    int e = (sw*256 + tid)*8;            // short index, 0..32767
    int frag = e >> 9;                   // (hl*2+kk)*8 + ctl
    int hkk = frag >> 3, ctl = frag & 7;
    GLDS(mfb + ((size_t)hkk*16 + ch*8 + ctl)*512 + (e & 511), lsB + e);
  }
  // ---- burst-load full A K-row: a[h*4+q], q = kk*2 + half
  float4 a[32];
  #pragma unroll
  for (int h = 0; h < 8; ++h) {
    #pragma unroll
    for (int q = 0; q < 4; ++q)
      a[h*4+q] = *(const float4*)(wb + (size_t)h*NMESH*64 + (q>>1)*32 + (q&1)*4);
  }
  __builtin_amdgcn_sched_barrier(0);
  // B half-0 staged (16 GLDS are the oldest vmem ops; 32 A loads may float)
  asm volatile("s_waitcnt vmcnt(32)" ::: "memory");
  __builtin_amdgcn_s_barrier();
  __builtin_amdgcn_sched_barrier(0);

  f32x4 acc[8];
  #pragma unroll
  for (int i = 0; i < 8; ++i) acc[i] = (f32x4){0,0,0,0};

  #pragma unroll
  for (int ks = 0; ks < 8; ++ks) {       // h = ks>>1, kk = ks&1
    float4 lo = a[(ks>>1)*4 + (ks&1)*2];
    float4 hi = a[(ks>>1)*4 + (ks&1)*2 + 1];
    short8v af;
    af[0] = (short)f2bf(lo.x); af[1] = (short)f2bf(lo.y);
    af[2] = (short)f2bf(lo.z); af[3] = (short)f2bf(lo.w);
    af[4] = (short)f2bf(hi.x); af[5] = (short)f2bf(hi.y);
    af[6] = (short)f2bf(hi.z); af[7] = (short)f2bf(hi.w);
    const unsigned short* lb = lsB + (size_t)ks*8*512 + lane*8;
    #pragma unroll
    for (int ct = 0; ct < 8; ++ct) {
      short8v bf = *(const short8v*)(lb + ct*512);
      acc[ct] = __builtin_amdgcn_mfma_f32_16x16x32_bf16(af, bf, acc[ct], 0, 0, 0);
    }
  }
  __syncthreads();                       // all waves done reading half 0
  // ---- stage B half 1 (h 4..7)
  #pragma unroll
  for (int sw = 0; sw < 16; ++sw) {
    int e = (sw*256 + tid)*8;
    int frag = e >> 9;
    int hkk = frag >> 3, ctl = frag & 7;
    GLDS(mfb + ((size_t)(8 + hkk)*16 + ch*8 + ctl)*512 + (e & 511), lsB + e);
  }
  __builtin_amdgcn_sched_barrier(0);
  __syncthreads();                       // half 1 landed
  #pragma unroll
  for (int ks = 8; ks < 16; ++ks) {
    float4 lo = a[(ks>>1)*4 + (ks&1)*2];
    float4 hi = a[(ks>>1)*4 + (ks&1)*2 + 1];
    short8v af;
    af[0] = (short)f2bf(lo.x); af[1] = (short)f2bf(lo.y);
    af[2] = (short)f2bf(lo.z); af[3] = (short)f2bf(lo.w);
    af[4] = (short)f2bf(hi.x); af[5] = (short)f2bf(hi.y);
    af[6] = (short)f2bf(hi.z); af[7] = (short)f2bf(hi.w);
    const unsigned short* lb = lsB + (size_t)(ks-8)*8*512 + lane*8;
    #pragma unroll
    for (int ct = 0; ct < 8; ++ct) {
      short8v bf = *(const short8v*)(lb + ct*512);
      acc[ct] = __builtin_amdgcn_mfma_f32_16x16x32_bf16(af, bf, acc[ct], 0, 0, 0);
    }
  }

  // ---- epilogue: C layout col=lane&15, row=(lane>>4)*4+r
  int rb = n0 + wv*16 + kg*4;
  #pragma unroll
  for (int ct = 0; ct < 8; ++ct) {
    int colg = ch*128 + ct*16 + r16;
    float bias = tob[colg];
    #pragma unroll
    for (int r = 0; r < 4; ++r) {
      int rr = rb + r;
      if (rr < NMESH)
        out[((size_t)b*NMESH + rr)*DOUT + colg] = acc[ct][r] + bias;
    }
  }
}

// ----------------------------------------------------------------
extern "C" void kernel_launch(void* const* d_in, const int* in_sizes, int n_in,
                              void* d_out, int out_size, void* d_ws, size_t ws_size,
                              hipStream_t stream) {
  (void)in_sizes; (void)n_in; (void)out_size; (void)ws_size;
  const float* st   = (const float*)d_in[0];
  const float* sw   = (const float*)d_in[1];
  const float* ipw  = (const float*)d_in[2];
  const float* cw   = (const float*)d_in[3];
  const float* cb   = (const float*)d_in[4];
  const float* dtb  = (const float*)d_in[5];
  const float* alog = (const float*)d_in[6];
  const float* fcD  = (const float*)d_in[7];
  const float* Dd   = (const float*)d_in[8];
  const float* nw   = (const float*)d_in[9];
  const float* opw  = (const float*)d_in[10];
  const float* tow  = (const float*)d_in[11];
  const float* tob  = (const float*)d_in[12];
  float* out = (float*)d_out;
  unsigned char* ws = (unsigned char*)d_ws;

  float* zx = (float*)(ws + 0);                          // 2*64*2208*4 = 1130496
  float* yb = (float*)(ws + 1130496);                    // 4*64*1024*4 = 1048576
  unsigned short* mfr = (unsigned short*)(ws + 2179072); // 512 KB

  k_inproj   <<<dim3(9, 16), 256, 0, stream>>>(st, ipw, zx);
  k_scanconv <<<64,  256, 0, stream>>>(zx, cw, cb, dtb, alog, yb);
  k_combo    <<<128, 256, 0, stream>>>(zx, yb, fcD, Dd, nw, opw, tow, cw, cb, mfr);
  k_out_gemm <<<dim3(2*((NMESH + 63)/64), NB), 256, 0, stream>>>(sw, mfr, tob, out);
}

// Round 6
// 327.709 us; speedup vs baseline: 1.2952x; 1.2952x over previous
//
#include <hip/hip_runtime.h>
#include <hip/hip_bf16.h>
#include <math.h>

#define NB 2
#define LL 64
#define NMESH 100000
#define HEADS_O 8
#define DHC 64
#define DMODEL 512
#define DINNER 1024
#define DSTATE 64
#define NH 16
#define CONVDIM 1152
#define DINPROJ 2208
#define DOUT 256
#define NCHUNK 6250   // 100000 / 16, exact

typedef __attribute__((ext_vector_type(8))) short short8v;   // 8 x bf16
typedef __attribute__((ext_vector_type(4))) float f32x4;

__device__ __forceinline__ unsigned short f2bf(float f) {
  union { float f; unsigned u; } v; v.f = f;
  unsigned u = v.u;
  u += 0x7FFFu + ((u >> 16) & 1u);
  return (unsigned short)(u >> 16);
}

__device__ __forceinline__ float dot4(float4 a, const float* b) {
  return a.x*b[0] + a.y*b[1] + a.z*b[2] + a.w*b[3];
}

__device__ __forceinline__ float silu(float s) { return s / (1.f + expf(-s)); }

// ---------------------------------------------------------------- K1: in_proj (weight-streaming)
__global__ void k_inproj(const float* __restrict__ st, const float* __restrict__ w,
                         float* __restrict__ zx) {
  int oc = blockIdx.x;             // 0..8 : o = oc*256 + t
  int blc = blockIdx.y;            // 0..15: bl = blc*8 + r
  int t = threadIdx.x;
  __shared__ float u[8][DMODEL];   // 16 KB
  for (int idx = t; idx < 8*DMODEL; idx += 256) {
    int r = idx >> 9, m = idx & 511;
    int bl = blc*8 + r; int b = bl >> 6, l = bl & 63;
    u[r][m] = st[((size_t)(b*HEADS_O + (m >> 6))*LL + l)*DHC + (m & 63)];
  }
  __syncthreads();
  int o = oc*256 + t;
  if (o < DINPROJ) {
    const float4* wr = (const float4*)(w + (size_t)o*DMODEL);
    float acc[8] = {0,0,0,0,0,0,0,0};
    for (int m4 = 0; m4 < DMODEL/4; ++m4) {
      float4 wv = wr[m4];
      #pragma unroll
      for (int r = 0; r < 8; ++r) acc[r] += dot4(wv, &u[r][m4*4]);
    }
    #pragma unroll
    for (int r = 0; r < 8; ++r)
      zx[(size_t)(blc*8 + r)*DINPROJ + o] = acc[r];
  }
}

// ---------------------------------------------------------------- K2: fused conv+silu AND dt softplus
__global__ void k_convdt(const float* __restrict__ zx, const float* __restrict__ cw,
                         const float* __restrict__ cb, const float* __restrict__ dtb,
                         float* __restrict__ conv_out, float* __restrict__ dtbuf) {
  if (blockIdx.x < 576) {
    int i = blockIdx.x*256 + threadIdx.x;           // < 147456
    int c = i % CONVDIM; int l = (i / CONVDIM) % LL; int b = i / (CONVDIM*LL);
    float s = cb[c];
    #pragma unroll
    for (int k = 0; k < 3; ++k) {
      int tt = l - 1 + k;
      if (tt >= 0 && tt < LL)
        s += cw[c*3 + k] * zx[(size_t)(b*LL + tt)*DINPROJ + DINNER + c];
    }
    conv_out[i] = silu(s);
  } else {
    int i = (blockIdx.x - 576)*256 + threadIdx.x;   // (s*64+l)*16+h, 4096 total
    if (i < 4*LL*NH) {
      int h = i & 15, l = (i >> 4) & 63, s = i >> 10;
      float v;
      if (s < 2)
        v = zx[(size_t)(s*LL + l)*DINPROJ + (DINNER + CONVDIM) + h];
      else
        v = zx[(size_t)((s-2)*LL + (63-l))*DINPROJ + (DINNER + CONVDIM) + 16 + h];
      v += dtb[h];
      dtbuf[i] = (v > 20.f) ? v : log1pf(expf(v));
    }
  }
}

// ---------------------------------------------------------------- K3: SSD scan (parallel form)
__global__ void k_scan(const float* __restrict__ conv_out, const float* __restrict__ dtbuf,
                       const float* __restrict__ A_log, float* __restrict__ ybuf) {
  int blk = blockIdx.x;
  int s = blk >> 4, hh = blk & 15;
  int b = s & 1;
  bool rev = (s >= 2);
  int t = threadIdx.x;
  int wv = t >> 6, lane = t & 63;
  __shared__ float Bs[64*68];
  __shared__ float Cs[64*68];
  __shared__ float Xs[64*64];
  __shared__ float dts[64];
  __shared__ float Dc[64];

  for (int id = t; id < 4096; id += 256) {
    int tt0 = id >> 6, n = id & 63;
    int tt = rev ? (63 - tt0) : tt0;
    size_t base = (size_t)(b*LL + tt) * CONVDIM;
    Xs[tt0*64 + n] = conv_out[base + hh*64 + n];
    Bs[tt0*68 + n] = conv_out[base + DINNER + n];
    Cs[tt0*68 + n] = conv_out[base + DINNER + DSTATE + n];
  }
  if (t < 64) dts[t] = dtbuf[(size_t)(s*LL + t)*NH + hh];
  __syncthreads();
  if (t < 64) {
    float v = dts[t];
    #pragma unroll
    for (int m = 1; m < 64; m <<= 1) {
      float o = __shfl_up(v, m, 64);
      if (lane >= m) v += o;
    }
    Dc[t] = v;
  }
  __syncthreads();
  float A = -expf(A_log[hh]);
  float g[16];
  #pragma unroll
  for (int i = 0; i < 16; ++i) {
    int tt = wv + 4*i;
    int ta = lane;
    float gv = 0.f;
    if (ta <= tt) {
      const float* Br = &Bs[ta*68];
      const float* Cr = &Cs[tt*68];
      float dot = 0.f;
      #pragma unroll
      for (int n4 = 0; n4 < 16; ++n4) {
        float4 bv = *(const float4*)&Br[n4*4];
        float4 cv = *(const float4*)&Cr[n4*4];
        dot += bv.x*cv.x + bv.y*cv.y + bv.z*cv.z + bv.w*cv.w;
      }
      gv = dot * expf(A * (Dc[tt] - Dc[ta])) * dts[ta];
    }
    g[i] = gv;
  }
  __syncthreads();
  #pragma unroll
  for (int i = 0; i < 16; ++i) Bs[(wv + 4*i)*64 + lane] = g[i];
  __syncthreads();
  for (int id = t; id < 4096; id += 256) {
    int tt = id >> 6, p = id & 63;
    float y = 0.f;
    for (int ta = 0; ta <= tt; ++ta) y += Bs[tt*64 + ta] * Xs[ta*64 + p];
    ybuf[(size_t)(s*LL + tt)*DINNER + hh*64 + p] = y;
  }
}

// ---------------------------------------------------------------- K4: combine + gate + RMS + out_proj + mfrag (fused)
__global__ void k_combo2(const float* __restrict__ conv_out, const float* __restrict__ zx,
                         const float* __restrict__ yb, const float* __restrict__ fcD,
                         const float* __restrict__ Dd, const float* __restrict__ nw,
                         const float* __restrict__ opw, const float* __restrict__ tow,
                         unsigned short* __restrict__ mfp) {
  int bl = blockIdx.x; int b = bl >> 6, l = bl & 63;
  int t = threadIdx.x;
  __shared__ float xog[DINNER];
  __shared__ float yrow[DINNER];
  __shared__ float ohs[DMODEL];
  __shared__ float diag[NH];
  __shared__ float wsum[4];
  #pragma unroll
  for (int i = 0; i < 4; ++i) {
    int c = t + 256*i;
    xog[c] = conv_out[(size_t)bl*CONVDIM + c];
  }
  __syncthreads();
  {
    int hh = t >> 4, j = t & 15;
    const float* fr = fcD + (size_t)hh*DINNER;
    float acc = 0.f;
    for (int k = 0; k < 64; ++k) acc += xog[j + 16*k] * fr[j + 16*k];
    #pragma unroll
    for (int m = 8; m >= 1; m >>= 1) acc += __shfl_xor(acc, m, 64);
    if (j == 0) diag[hh] = acc + Dd[hh];
  }
  __syncthreads();
  float ss = 0.f;
  float y2v[4];
  #pragma unroll
  for (int i = 0; i < 4; ++i) {
    int c = t + 256*i;
    float yf = (l == 0)  ? 0.f : yb[(size_t)(b*LL + l - 1)*DINNER + c];
    float yw = (l == 63) ? 0.f : yb[(size_t)((2+b)*LL + 62 - l)*DINNER + c];
    float y1 = yf + yw + xog[c]*diag[c >> 6];
    float z = zx[(size_t)bl*DINPROJ + c];
    float y2 = y1 * silu(z);
    y2v[i] = y2;
    ss += y2*y2;
  }
  #pragma unroll
  for (int m = 32; m >= 1; m >>= 1) ss += __shfl_xor(ss, m, 64);
  if ((t & 63) == 0) wsum[t >> 6] = ss;
  __syncthreads();
  float tot = wsum[0] + wsum[1] + wsum[2] + wsum[3];
  float scale = rsqrtf(tot * (1.f/1024.f) + 1e-5f);
  #pragma unroll
  for (int i = 0; i < 4; ++i) {
    int c = t + 256*i;
    yrow[c] = y2v[i] * scale * nw[c];
  }
  __syncthreads();
  // out_proj: 512 outs, 2 per thread
  #pragma unroll
  for (int oi = 0; oi < 2; ++oi) {
    int o = t + 256*oi;
    const float4* wr = (const float4*)(opw + (size_t)o*DINNER);
    float acc = 0.f;
    #pragma unroll 4
    for (int k4 = 0; k4 < DINNER/4; ++k4) acc += dot4(wr[k4], &yrow[k4*4]);
    ohs[o] = acc;
  }
  __syncthreads();
  // mfrag: M[b,h,g,d] = sum_c ohs[h*64+c]*tow[d,h*64+c]; this block owns g = l
  int g = l;
  int kkq = g >> 5;
  int lnhi = ((g & 31) >> 3) << 4;
  int j = g & 7;
  #pragma unroll
  for (int ii = 0; ii < 8; ++ii) {
    int idx = t + 256*ii;            // (h,d)
    int h = idx >> 8, d = idx & 255;
    const float4* wr = (const float4*)(tow + (size_t)d*DMODEL + h*64);
    const float* op = &ohs[h*64];
    float acc = 0.f;
    #pragma unroll
    for (int c4 = 0; c4 < 16; ++c4) acc += dot4(wr[c4], &op[c4*4]);
    int ln = (d & 15) | lnhi;
    mfp[((((size_t)(b*HEADS_O + h)*2 + kkq)*16 + (d >> 4))*64 + ln)*8 + j] = f2bf(acc);
  }
}

// ---------------------------------------------------------------- K5: persistent streaming GEMM (coverage-fixed)
// out[b,n,d] = sum_{h,g} W[b,h,n,g]*M[b,h,g,d] + tob[d]
// 256 blocks x 512 thr (8 waves, 1 block/CU). Block = (rg, b, ch):
// B panel (128 cols x K=512, bf16) in 128 KB LDS, reg-staged ONCE (1 barrier).
// Each wave streams 16-row chunks c = wv*64+rg+512k and computes ALL 8
// column tiles (acc[8]) of the block's 128-col panel. A uses an 8-group
// in-place ring a[8][4]: step h converts/MFMAs chunk-c group h while issuing
// chunk-(c+512) group h -> one full iteration (~600cy) of load lead, no
// per-iteration barriers, loads never stop issuing.
__global__ __launch_bounds__(512, 1) void k_out_gemm(const float* __restrict__ W,
                                                     const unsigned short* __restrict__ mf,
                                                     const float* __restrict__ tob,
                                                     float* __restrict__ out) {
  int bx = blockIdx.x;              // rg*4 + b*2 + ch  (ch fastest -> L3 twin pairing)
  int rg = bx >> 2;                 // 0..63
  int b  = (bx >> 1) & 1;
  int ch = bx & 1;
  int tid = threadIdx.x;
  int wv = tid >> 6, lane = tid & 63;
  int r16 = lane & 15, kg = lane >> 4;

  __shared__ __align__(16) unsigned short lsB[16*8*512];   // [ks][ct'][ln][8] = 128 KB

  // ---- stage B panel once via registers (compiler-tracked)
  {
    const unsigned short* mfb = mf + (size_t)b*(16*16*512);
    uint4 tmp[16];
    #pragma unroll
    for (int sw = 0; sw < 16; ++sw) {
      int i16 = sw*512 + tid;                 // 0..8191 16B-units
      int ks = i16 >> 9, rem = i16 & 511;
      int ctp = rem >> 6, ln = rem & 63;
      tmp[sw] = *(const uint4*)(mfb + ((size_t)(ks*16 + ch*8 + ctp)*64 + ln)*8);
    }
    #pragma unroll
    for (int sw = 0; sw < 16; ++sw) {
      int i16 = sw*512 + tid;
      *(uint4*)(lsB + (size_t)i16*8) = tmp[sw];
    }
  }
  __syncthreads();                            // the only barrier

  int colg0 = ch*128 + r16;
  const size_t hstride = (size_t)NMESH*64;
  int c = wv*64 + rg;                         // first chunk (always < NCHUNK)
  const float* wb = W + ((size_t)b*HEADS_O*NMESH + (size_t)c*16 + r16)*64 + kg*8;

  float4 a[8][4];                             // [head][kk0lo,kk0hi,kk1lo,kk1hi]
  #pragma unroll
  for (int h = 0; h < 8; ++h) {
    const float* p = wb + (size_t)h*hstride;
    a[h][0] = *(const float4*)p;
    a[h][1] = *(const float4*)(p + 4);
    a[h][2] = *(const float4*)(p + 32);
    a[h][3] = *(const float4*)(p + 36);
  }

  while (c < NCHUNK) {
    int cn = c + 512;                         // 8 waves * 64 rowgroups
    const float* wbn = (cn < NCHUNK) ? (wb + (size_t)8192*64) : wb;
    f32x4 acc[8];
    #pragma unroll
    for (int ct = 0; ct < 8; ++ct) acc[ct] = (f32x4){0.f,0.f,0.f,0.f};

    #pragma unroll
    for (int h = 0; h < 8; ++h) {
      short8v af0, af1;                       // convert current chunk's group h
      af0[0] = (short)f2bf(a[h][0].x); af0[1] = (short)f2bf(a[h][0].y);
      af0[2] = (short)f2bf(a[h][0].z); af0[3] = (short)f2bf(a[h][0].w);
      af0[4] = (short)f2bf(a[h][1].x); af0[5] = (short)f2bf(a[h][1].y);
      af0[6] = (short)f2bf(a[h][1].z); af0[7] = (short)f2bf(a[h][1].w);
      af1[0] = (short)f2bf(a[h][2].x); af1[1] = (short)f2bf(a[h][2].y);
      af1[2] = (short)f2bf(a[h][2].z); af1[3] = (short)f2bf(a[h][2].w);
      af1[4] = (short)f2bf(a[h][3].x); af1[5] = (short)f2bf(a[h][3].y);
      af1[6] = (short)f2bf(a[h][3].z); af1[7] = (short)f2bf(a[h][3].w);
      {                                       // issue next chunk's group h
        const float* np = wbn + (size_t)h*hstride;
        a[h][0] = *(const float4*)np;
        a[h][1] = *(const float4*)(np + 4);
        a[h][2] = *(const float4*)(np + 32);
        a[h][3] = *(const float4*)(np + 36);
      }
      __builtin_amdgcn_sched_barrier(0);
      const unsigned short* lb0 = lsB + (size_t)(2*h)*4096 + lane*8;
      #pragma unroll
      for (int ct = 0; ct < 8; ++ct) {
        short8v bf0 = *(const short8v*)(lb0 + ct*512);
        short8v bf1 = *(const short8v*)(lb0 + 4096 + ct*512);
        acc[ct] = __builtin_amdgcn_mfma_f32_16x16x32_bf16(af0, bf0, acc[ct], 0, 0, 0);
        acc[ct] = __builtin_amdgcn_mfma_f32_16x16x32_bf16(af1, bf1, acc[ct], 0, 0, 0);
      }
      __builtin_amdgcn_sched_barrier(0);
    }
    // store: C layout col=lane&15, row=(lane>>4)*4+r
    int rb = c*16 + kg*4;
    #pragma unroll
    for (int ct = 0; ct < 8; ++ct) {
      int colg = colg0 + ct*16;
      float bias = tob[colg];
      #pragma unroll
      for (int r = 0; r < 4; ++r)
        out[((size_t)b*NMESH + rb + r)*DOUT + colg] = acc[ct][r] + bias;
    }
    c = cn;
    wb = wbn;
  }
}

// ----------------------------------------------------------------
extern "C" void kernel_launch(void* const* d_in, const int* in_sizes, int n_in,
                              void* d_out, int out_size, void* d_ws, size_t ws_size,
                              hipStream_t stream) {
  (void)in_sizes; (void)n_in; (void)out_size; (void)ws_size;
  const float* st   = (const float*)d_in[0];
  const float* sw   = (const float*)d_in[1];
  const float* ipw  = (const float*)d_in[2];
  const float* cw   = (const float*)d_in[3];
  const float* cb   = (const float*)d_in[4];
  const float* dtb  = (const float*)d_in[5];
  const float* alog = (const float*)d_in[6];
  const float* fcD  = (const float*)d_in[7];
  const float* Dd   = (const float*)d_in[8];
  const float* nw   = (const float*)d_in[9];
  const float* opw  = (const float*)d_in[10];
  const float* tow  = (const float*)d_in[11];
  const float* tob  = (const float*)d_in[12];
  float* out = (float*)d_out;
  unsigned char* ws = (unsigned char*)d_ws;

  float* zx   = (float*)(ws + 0);            // 2*64*2208*4   = 1130496
  float* conv = (float*)(ws + 1130496);      // 2*64*1152*4   = 589824
  float* dtp  = (float*)(ws + 1720320);      // 4*64*16*4     = 16384
  float* yb   = (float*)(ws + 1736704);      // 4*64*1024*4   = 1048576
  unsigned short* mfr = (unsigned short*)(ws + 2785280);  // 524288

  k_inproj  <<<dim3(9, 16), 256, 0, stream>>>(st, ipw, zx);
  k_convdt  <<<592, 256, 0, stream>>>(zx, cw, cb, dtb, conv, dtp);
  k_scan    <<<64,  256, 0, stream>>>(conv, dtp, alog, yb);
  k_combo2  <<<128, 256, 0, stream>>>(conv, zx, yb, fcD, Dd, nw, opw, tow, mfr);
  k_out_gemm<<<256, 512, 0, stream>>>(sw, mfr, tob, out);
}